// Round 16
// baseline (131.055 us; speedup 1.0000x reference)
//
#include <hip/hip_runtime.h>
#include <hip/hip_bf16.h>
#include <math.h>

#define N 8192
#define D 256
#define MARGIN 1.0f

#define BM 128
#define BN 128
#define NCH 4            // K-chunks of 64 fp16 elems (128B per row)
#define NB (N / BM)      // 64
#define NTRI (NB * (NB + 1) / 2)   // 2080
#define NCONV (N * D / 4 / 256)    // 2048 conversion blocks
#define NCLS 512
#define CCAP 64          // class member capacity (mean 16)
#define RPITCH 257       // padded row pitch (floats) -> conflict-free LDS

typedef __attribute__((ext_vector_type(8))) _Float16 half8;
typedef __attribute__((ext_vector_type(4))) _Float16 half4;
typedef __attribute__((ext_vector_type(4))) float f32x4;
typedef unsigned int uint32;
typedef unsigned long long u64;

// ---------------------------------------------------------------------------
// k_prep: blocks [0,NCONV): f32->fp16 conversion (+ block 0 zeroes the
// finish cells). Blocks [NCONV,+NCLS): per-class exact-f32 d_pos,
// LDS-resident (r15-proven).
// ---------------------------------------------------------------------------
__global__ __launch_bounds__(256) void k_prep(const float* __restrict__ x,
                                              const int* __restrict__ labels,
                                              _Float16* __restrict__ hp,
                                              float* __restrict__ dpos,
                                              u64* __restrict__ acc_pack,
                                              unsigned* __restrict__ counter,
                                              unsigned* __restrict__ done_ctr) {
    const int b = blockIdx.x;
    const int t = threadIdx.x;

    if (b < NCONV) {
        int i = b * 256 + t;
        float4 v = reinterpret_cast<const float4*>(x)[i];
        half4 h;
        h[0] = (_Float16)v.x; h[1] = (_Float16)v.y;
        h[2] = (_Float16)v.z; h[3] = (_Float16)v.w;
        reinterpret_cast<half4*>(hp)[i] = h;
        if (b == 0 && t == 0) {
            *acc_pack = 0ull;
            *counter = 0u;
            *done_ctr = 0u;
        }
        return;
    }

    __shared__ float rows[CCAP * RPITCH];   // 65792 B
    __shared__ float sqv[CCAP];
    __shared__ int dpv[CCAP];               // sqd bits (>=0 -> int cmp ok)
    __shared__ int mem[CCAP];
    __shared__ int nmem;

    const int c = b - NCONV;
    if (t == 0) nmem = 0;
    if (t < CCAP) dpv[t] = 0;
    __syncthreads();
    for (int base = 0; base < N; base += 256) {
        int j = base + t;
        if (labels[j] == c) {
            int p = atomicAdd(&nmem, 1);
            if (p < CCAP) mem[p] = j;
        }
    }
    __syncthreads();
    const int M = nmem < CCAP ? nmem : CCAP;

    for (int r = 0; r < M; ++r)
        rows[r * RPITCH + t] = x[(size_t)mem[r] * D + t];
    __syncthreads();

    if (t < M) {
        const float* rp = &rows[t * RPITCH];
        float s = 0.0f;
        for (int d = 0; d < D; ++d) s += rp[d] * rp[d];
        sqv[t] = s;
    }
    __syncthreads();

    for (int p = t; p < M * M; p += 256) {
        int i = p / M, j = p - i * M;
        const float* ri = &rows[i * RPITCH];
        const float* rj = &rows[j * RPITCH];
        float dot = 0.0f;
        for (int d = 0; d < D; ++d) dot = fmaf(ri[d], rj[d], dot);
        float sqd = fmaxf(sqv[i] + sqv[j] - 2.0f * dot, 0.0f);
        if (j != i) atomicMax(&dpv[i], __float_as_int(sqd));
    }
    __syncthreads();
    if (t < M)
        dpos[mem[t]] = (M > 1) ? sqrtf(__int_as_float(dpv[t])) : -1.0f;
}

// ---------------------------------------------------------------------------
// k_main: tile blocks [0,NTRI) = r15-proven symmetric fp16 MFMA GEMM with
// key-free epilogue; partials published with DEVICE-SCOPE stores (per-XCD
// L2s are not coherent; graph replay leaves stale lines), then done_ctr++.
// Tail blocks [NTRI, NTRI+NB): spin on done_ctr (thread 0, s_sleep), then
// fold partials with device-scope loads, compute per-anchor loss from the
// exact f32 maxima, one packed-integer atomicAdd; last tail block writes out.
// ---------------------------------------------------------------------------
__global__ __launch_bounds__(512) void k_main(const _Float16* __restrict__ hp,
                                              const int* __restrict__ labels,
                                              const float* __restrict__ dpos,
                                              float* __restrict__ pr_n,
                                              float* __restrict__ pr_s,
                                              float* __restrict__ pc_n,
                                              float* __restrict__ pc_s,
                                              u64* __restrict__ acc_pack,
                                              unsigned* __restrict__ counter,
                                              unsigned* __restrict__ done_ctr,
                                              float* __restrict__ out) {
    const int t = threadIdx.x;
    const float NINF = -__builtin_inff();

    if (blockIdx.x >= NTRI) {
        // ---------------- finish tail block ----------------
        __shared__ float shn[4][128], shs[4][128];
        __shared__ u64 wpart[2];
        const int q = blockIdx.x - NTRI;
        const int part = t >> 7, a = t & 127;
        const int Lr = NB - q;
        const int base = q * NB - q * (q - 1) / 2;
        const int ntiles = Lr + q + 1;

        if (t == 0) {
            while (__hip_atomic_load(done_ctr, __ATOMIC_RELAXED,
                                     __HIP_MEMORY_SCOPE_AGENT) < NTRI)
                __builtin_amdgcn_s_sleep(8);
        }
        __syncthreads();
        __threadfence();

        float an = NINF, ag = NINF;
        for (int u = part; u < ntiles; u += 4) {
            size_t off;
            const float *Pn, *Ps;
            if (u < Lr) {
                off = (size_t)(base + u) * BM + a;
                Pn = pr_n; Ps = pr_s;
            } else {
                int byy = u - Lr;
                int tb2 = byy * NB - byy * (byy - 1) / 2 + (q - byy);
                off = (size_t)tb2 * BN + a;
                Pn = pc_n; Ps = pc_s;
            }
            an = fmaxf(an, __hip_atomic_load(&Pn[off], __ATOMIC_RELAXED,
                                             __HIP_MEMORY_SCOPE_AGENT));
            ag = fmaxf(ag, __hip_atomic_load(&Ps[off], __ATOMIC_RELAXED,
                                             __HIP_MEMORY_SCOPE_AGENT));
        }
        shn[part][a] = an;
        shs[part][a] = ag;
        __syncthreads();

        u64 pack = 0;
        if (t < 128) {
            an = fmaxf(fmaxf(shn[0][t], shn[1][t]), fmaxf(shn[2][t], shn[3][t]));
            ag = fmaxf(fmaxf(shs[0][t], shs[1][t]), fmaxf(shs[2][t], shs[3][t]));
            float dp = dpos[q * 128 + t];
            if (dp >= 0.0f && an > -1e37f) {
                float dphi = dp + MARGIN;
                float aLo = (2.0f - dphi * dphi) * 0.5f;
                float asel = (ag > aLo) ? ag : an;
                float fsq = fmaxf(fmaf(-2.0f, asel, 2.0f), 0.0f);
                float dn = sqrtf(fsq);
                float l = fmaxf(dp - dn + MARGIN, 0.0f);
                u64 lq = (u64)(l * 1073741824.0f + 0.5f);
                pack = (lq << 16) | 1ull;
            }
        }
        for (int m = 1; m <= 32; m <<= 1) pack += __shfl_xor(pack, m, 64);
        if (t < 128 && (t & 63) == 0) wpart[t >> 6] = pack;
        __syncthreads();
        if (t == 0) {
            atomicAdd(acc_pack, wpart[0] + wpart[1]);
            __threadfence();
            unsigned old = atomicAdd(counter, 1u);
            if (old == NB - 1) {
                u64 val = atomicAdd(acc_pack, (u64)0);
                double s = (double)(val >> 16) * (1.0 / 1073741824.0);
                double c = (double)(val & 0xFFFFull);
                out[0] = (float)(s / c);
            }
        }
        return;
    }

    // ---------------- tile block (r15 core, device-scope partial stores) ----
    __shared__ char Abuf[2][BM * 128];   // 16 KB each
    __shared__ char Bbuf[2][BN * 128];
    __shared__ float rHi[BM], cHi[BN];
    __shared__ int rlab[BM], clab[BN];
    __shared__ float tmpn[4][BM], tmps[4][BM];

    int tb = blockIdx.x;
    int by = (int)((2 * NB + 1 - sqrtf((float)((2 * NB + 1) * (2 * NB + 1)) -
                                       8.0f * (float)tb)) * 0.5f);
    if (by < 0) by = 0;
    if (by > NB - 1) by = NB - 1;
    while (by > 0 && (by * NB - by * (by - 1) / 2) > tb) --by;
    while (((by + 1) * NB - (by + 1) * by / 2) <= tb) ++by;
    const int bx = by + (tb - (by * NB - by * (by - 1) / 2));
    const int r0 = by * BM, c0 = bx * BN;

    const int w = t >> 6, lane = t & 63;
    const int wr = w >> 2, wc = w & 3;   // 2x4 wave grid; 64x32 per wave

    if (t < BM) {
        rlab[t] = labels[r0 + t];
        float dp = dpos[r0 + t];
        rHi[t] = (2.0f - dp * dp) * 0.5f;   // a < aHi <=> dist > dp
    } else if (t < 256) {
        int u = t - BM;
        clab[u] = labels[c0 + u];
        float dp = dpos[c0 + u];
        cHi[u] = (2.0f - dp * dp) * 0.5f;
    }

    f32x4 acc[4][2] = {};    // [m][n]
    f32x4 accT[2][4] = {};   // [n][m]

    const int srow = lane >> 3;
    const int scol = ((lane & 7) ^ srow) << 3;   // fp16-elem offset
    const _Float16* gA0 = hp + (size_t)(r0 + srow) * D + scol + (size_t)w * 8 * D;
    const _Float16* gB0 = hp + (size_t)(c0 + srow) * D + scol + (size_t)w * 8 * D;
    const int ldso = w * 1024 + lane * 16;

#define STAGE(bufA, bufB, k0e)                                                  \
    {                                                                           \
        _Pragma("unroll")                                                       \
        for (int q2 = 0; q2 < 2; ++q2) {                                        \
            const _Float16* gpa = gA0 + q2 * (8 * 8 * D) + (k0e);               \
            const _Float16* gpb = gB0 + q2 * (8 * 8 * D) + (k0e);               \
            char* lpa = (bufA) + q2 * 8192 + ldso;                              \
            char* lpb = (bufB) + q2 * 8192 + ldso;                              \
            __builtin_amdgcn_global_load_lds(                                   \
                (__attribute__((address_space(1))) void*)(void*)gpa,            \
                (__attribute__((address_space(3))) void*)lpa, 16, 0, 0);        \
            __builtin_amdgcn_global_load_lds(                                   \
                (__attribute__((address_space(1))) void*)(void*)gpb,            \
                (__attribute__((address_space(3))) void*)lpb, 16, 0, 0);        \
        }                                                                       \
    }

    STAGE(Abuf[0], Bbuf[0], 0);
    asm volatile("s_waitcnt vmcnt(0)" ::: "memory");
    __syncthreads();

    const int g2 = lane >> 4;
    const int lr = lane & 15;
    const int rsw = lr & 7;

#pragma unroll 1
    for (int s = 0; s < NCH; ++s) {
        const int cur = s & 1;
        if (s < NCH - 1) STAGE(Abuf[cur ^ 1], Bbuf[cur ^ 1], (s + 1) * 64);

#pragma unroll
        for (int kk = 0; kk < 2; ++kk) {
            const int cb = kk * 64 + (g2 << 4);
            half8 aF[4], bF[2];
#pragma unroll
            for (int m = 0; m < 4; ++m) {
                int ra = wr * 64 + m * 16 + lr;
                aF[m] = *reinterpret_cast<const half8*>(
                    Abuf[cur] + ra * 128 + (cb ^ (rsw << 4)));
            }
#pragma unroll
            for (int n = 0; n < 2; ++n) {
                int rb = wc * 32 + n * 16 + lr;
                bF[n] = *reinterpret_cast<const half8*>(
                    Bbuf[cur] + rb * 128 + (cb ^ (rsw << 4)));
            }
#pragma unroll
            for (int m = 0; m < 4; ++m)
#pragma unroll
                for (int n = 0; n < 2; ++n)
                    acc[m][n] = __builtin_amdgcn_mfma_f32_16x16x32_f16(
                        aF[m], bF[n], acc[m][n], 0, 0, 0);
#pragma unroll
            for (int n = 0; n < 2; ++n)
#pragma unroll
                for (int m = 0; m < 4; ++m)
                    accT[n][m] = __builtin_amdgcn_mfma_f32_16x16x32_f16(
                        bF[n], aF[m], accT[n][m], 0, 0, 0);
        }
        __syncthreads();
    }
#undef STAGE

    // ---- epilogue: key-free float maxima ----
    int rowm[4]; int rlm[4]; float rHim[4];
#pragma unroll
    for (int m = 0; m < 4; ++m) {
        rowm[m] = wr * 64 + m * 16 + lr;
        rlm[m] = rlab[rowm[m]];
        rHim[m] = rHi[rowm[m]];
    }
    int4 clA = *reinterpret_cast<const int4*>(&clab[wc * 32 + g2 * 4]);
    int4 clB = *reinterpret_cast<const int4*>(&clab[wc * 32 + 16 + g2 * 4]);
    const int clv[8] = {clA.x, clA.y, clA.z, clA.w, clB.x, clB.y, clB.z, clB.w};
    int coln[2]; int cln[2]; float cHin[2];
#pragma unroll
    for (int n = 0; n < 2; ++n) {
        coln[n] = wc * 32 + n * 16 + lr;
        cln[n] = clab[coln[n]];
        cHin[n] = cHi[coln[n]];
    }
    int rlq[16];
#pragma unroll
    for (int m = 0; m < 4; ++m) {
        int4 rv = *reinterpret_cast<const int4*>(&rlab[wr * 64 + m * 16 + g2 * 4]);
        rlq[m * 4 + 0] = rv.x; rlq[m * 4 + 1] = rv.y;
        rlq[m * 4 + 2] = rv.z; rlq[m * 4 + 3] = rv.w;
    }

    // row pass via accT
#pragma unroll
    for (int m = 0; m < 4; ++m) {
        const int rl = rlm[m];
        const float aHi = rHim[m];
        float an = NINF, ag = NINF;
#pragma unroll
        for (int n = 0; n < 2; ++n)
#pragma unroll
            for (int reg = 0; reg < 4; ++reg) {
                float a = accT[n][m][reg];
                bool neq = (rl != clv[n * 4 + reg]);
                an = fmaxf(an, neq ? a : NINF);
                ag = fmaxf(ag, (neq && a < aHi) ? a : NINF);
            }
        an = fmaxf(an, __shfl_xor(an, 16, 64));
        an = fmaxf(an, __shfl_xor(an, 32, 64));
        ag = fmaxf(ag, __shfl_xor(ag, 16, 64));
        ag = fmaxf(ag, __shfl_xor(ag, 32, 64));
        if (g2 == 0) {
            tmpn[wc][rowm[m]] = an;
            tmps[wc][rowm[m]] = ag;
        }
    }
    __syncthreads();
    if (t < BM) {
        float a0 = fmaxf(tmpn[0][t], tmpn[1][t]);
        float a1 = fmaxf(tmpn[2][t], tmpn[3][t]);
        __hip_atomic_store(&pr_n[(size_t)tb * BM + t], fmaxf(a0, a1),
                           __ATOMIC_RELAXED, __HIP_MEMORY_SCOPE_AGENT);
        float b0 = fmaxf(tmps[0][t], tmps[1][t]);
        float b1 = fmaxf(tmps[2][t], tmps[3][t]);
        __hip_atomic_store(&pr_s[(size_t)tb * BM + t], fmaxf(b0, b1),
                           __ATOMIC_RELAXED, __HIP_MEMORY_SCOPE_AGENT);
    }
    __syncthreads();

    // col pass via acc
#pragma unroll
    for (int n = 0; n < 2; ++n) {
        const int cl = cln[n];
        const float aHi = cHin[n];
        float an = NINF, ag = NINF;
#pragma unroll
        for (int m = 0; m < 4; ++m)
#pragma unroll
            for (int reg = 0; reg < 4; ++reg) {
                float a = acc[m][n][reg];
                bool neq = (cl != rlq[m * 4 + reg]);
                an = fmaxf(an, neq ? a : NINF);
                ag = fmaxf(ag, (neq && a < aHi) ? a : NINF);
            }
        an = fmaxf(an, __shfl_xor(an, 16, 64));
        an = fmaxf(an, __shfl_xor(an, 32, 64));
        ag = fmaxf(ag, __shfl_xor(ag, 16, 64));
        ag = fmaxf(ag, __shfl_xor(ag, 32, 64));
        if (lane < 16) {
            tmpn[wr][coln[n]] = an;
            tmps[wr][coln[n]] = ag;
        }
    }
    __syncthreads();
    if (t < BN) {
        __hip_atomic_store(&pc_n[(size_t)tb * BN + t],
                           fmaxf(tmpn[0][t], tmpn[1][t]),
                           __ATOMIC_RELAXED, __HIP_MEMORY_SCOPE_AGENT);
        __hip_atomic_store(&pc_s[(size_t)tb * BN + t],
                           fmaxf(tmps[0][t], tmps[1][t]),
                           __ATOMIC_RELAXED, __HIP_MEMORY_SCOPE_AGENT);
    }
    __syncthreads();
    if (t == 0) {
        __threadfence();
        atomicAdd(done_ctr, 1u);
    }
}

// ---------------------------------------------------------------------------
extern "C" void kernel_launch(void* const* d_in, const int* in_sizes, int n_in,
                              void* d_out, int out_size, void* d_ws, size_t ws_size,
                              hipStream_t stream) {
    const float* x = (const float*)d_in[0];
    const int* labels = (const int*)d_in[1];
    float* out = (float*)d_out;

    // ws: acc_pack u64 | counter u32 | done_ctr u32 | dpos[N]
    // | hp[N*D] fp16 | pr_n | pr_s | pc_n | pc_s (f32, 1.06MB each)
    u64* acc_pack = (u64*)d_ws;
    unsigned* counter = (unsigned*)(acc_pack + 1);
    unsigned* done_ctr = counter + 1;
    float* dpos = (float*)(done_ctr + 1);
    _Float16* hp = (_Float16*)(dpos + N);
    float* pr_n = (float*)(hp + (size_t)N * D);
    float* pr_s = pr_n + (size_t)NTRI * BM;
    float* pc_n = pr_s + (size_t)NTRI * BM;
    float* pc_s = pc_n + (size_t)NTRI * BM;

    hipLaunchKernelGGL(k_prep, dim3(NCONV + NCLS), dim3(256), 0, stream,
                       x, labels, hp, dpos, acc_pack, counter, done_ctr);
    hipLaunchKernelGGL(k_main, dim3(NTRI + NB), dim3(512), 0, stream,
                       hp, labels, dpos, pr_n, pr_s, pc_n, pc_s,
                       acc_pack, counter, done_ctr, out);
}